// Round 8
// baseline (5168.042 us; speedup 1.0000x reference)
//
#include <hip/hip_runtime.h>
#include <hip/hip_bf16.h>
#include <math.h>

// Problem constants
#define BSZ 64
#define TT  512
#define DD  512
#define UU  512
#define NZ  2048   // 4*U

#define NSL    32    // u-slices per batch-group
#define USL    16    // units per slice
#define NBG    8     // batch groups (= XCDs in LOCAL mode)
#define BG     8     // batches per group
#define KSTEPS 16    // 512 / 32 (MFMA k=32)

using short8  = __attribute__((ext_vector_type(8))) short;
using floatx4 = __attribute__((ext_vector_type(4))) float;

// ---------------------------------------------------------------------------
// Phase 1: zx = x @ Wk.  M=32768, K=512, N=2048. fp32 tiled GEMM (unchanged).
// ---------------------------------------------------------------------------
template <bool ZXBF16>
__global__ __launch_bounds__(256) void gemm_zx(const float* __restrict__ A,
                                               const float* __restrict__ B,
                                               void* __restrict__ Cout) {
  __shared__ float As[16][65];
  __shared__ float Bs[16][64];

  const int tid = threadIdx.x;
  const int tx = tid & 15;
  const int ty = tid >> 4;
  const int m0 = blockIdx.y * 64;
  const int n0 = blockIdx.x * 64;

  const int lm  = tid >> 2;
  const int lk4 = (tid & 3) * 4;
  const int lk  = tid >> 4;
  const int ln4 = (tid & 15) * 4;

  float acc[4][4] = {};

  for (int k0 = 0; k0 < DD; k0 += 16) {
    float4 av = *(const float4*)(A + (size_t)(m0 + lm) * DD + k0 + lk4);
    float4 bv = *(const float4*)(B + (size_t)(k0 + lk) * NZ + n0 + ln4);
    As[lk4 + 0][lm] = av.x;
    As[lk4 + 1][lm] = av.y;
    As[lk4 + 2][lm] = av.z;
    As[lk4 + 3][lm] = av.w;
    *(float4*)&Bs[lk][ln4] = bv;
    __syncthreads();
#pragma unroll
    for (int kk = 0; kk < 16; ++kk) {
      float a[4], b[4];
#pragma unroll
      for (int i = 0; i < 4; ++i) a[i] = As[kk][ty * 4 + i];
#pragma unroll
      for (int j = 0; j < 4; ++j) b[j] = Bs[kk][tx * 4 + j];
#pragma unroll
      for (int i = 0; i < 4; ++i)
#pragma unroll
        for (int j = 0; j < 4; ++j) acc[i][j] = fmaf(a[i], b[j], acc[i][j]);
    }
    __syncthreads();
  }

#pragma unroll
  for (int i = 0; i < 4; ++i) {
    const size_t row = (size_t)(m0 + ty * 4 + i) * NZ + n0 + tx * 4;
    if constexpr (ZXBF16) {
      __hip_bfloat16* C = (__hip_bfloat16*)Cout;
#pragma unroll
      for (int j = 0; j < 4; ++j) C[row + j] = __float2bfloat16(acc[i][j]);
    } else {
      float* C = (float*)Cout;
      *(float4*)&C[row] = make_float4(acc[i][0], acc[i][1], acc[i][2], acc[i][3]);
    }
  }
}

// ---------------------------------------------------------------------------
// Phase 2: ONE persistent kernel, 256 blocks x 256 threads, 1 block/CU
// (132 KiB LDS) -> all 256 CUs hold exactly one block; normally 32 per XCD.
//
// XCD-local role election: each block reads its physical XCC_ID (s_getreg,
// HW-verified) and claims (bg = xcd, sl = per-XCD ordinal) via counters in
// ws. Batch-group bg owns batches [8*bg, 8*bg+8); slice sl owns units
// [16*sl, 16*sl+16) x 4 gates. All h producers/consumers of a bg then share
// one XCD -> exchange through the XCD's L2 instead of the die-level MALL.
//
//   LOCAL mode (every XCD count == 32): h published with PLAIN stores
//   (write-through L1 -> local L2; vmcnt(0) drain at the post-epilogue
//   __syncthreads makes them XCD-visible), readers hit local L2 on
//   fresh-per-t addresses. Flags remain agent-scope atomics (MALL, proven).
//   GLOBAL mode (any uneven placement / bogus XCC_ID): all blocks detect it
//   from the counters; writers fall back to agent-scope atomic stores =
//   exactly the R7-proven protocol, correct on any placement.
//
// MFMA m=16 tile with the 8 batches duplicated into rows 8-15 (A rows
// addressed am&7): duplicate compute, no racing reads; C rows 8-15 ignored.
// All 256 blocks co-resident -> spin protocol cannot deadlock; election
// counters always reach 256.
// ---------------------------------------------------------------------------
__device__ __forceinline__ floatx4 mfma16(short8 a, short8 b, floatx4 c) {
  return __builtin_amdgcn_mfma_f32_16x16x32_bf16(a, b, c, 0, 0, 0);
}

template <bool ZXBF16>
__global__ __launch_bounds__(256) void lstm_persist(
    const void* __restrict__ zx_, const float* __restrict__ Wr,
    const float* __restrict__ bias, unsigned short* __restrict__ h_hi,
    unsigned short* __restrict__ h_lo, int* __restrict__ flags,
    int* __restrict__ elect, float* __restrict__ out) {
  extern __shared__ char lds[];
  unsigned short* wr_hi = (unsigned short*)lds;            // [K][g][lane][8]
  unsigned short* wr_lo = wr_hi + KSTEPS * 4 * 64 * 8;     // 32768 ushorts each
  float* z_ex = (float*)(wr_lo + KSTEPS * 4 * 64 * 8);     // [4 g][16 rows][16 u]
  int* s_meta = (int*)(z_ex + 4 * 16 * 16);                // bg, sl, mode

  const int tid = threadIdx.x;
  const int g = tid >> 6;             // wave = gate 0..3
  const int lane = tid & 63;

  // ---- role election (one-time) ----
  if (tid == 0) {
    int xcd;
    asm volatile("s_getreg_b32 %0, hwreg(HW_REG_XCC_ID)" : "=s"(xcd));
    xcd &= 7;
    const int local = __hip_atomic_fetch_add(elect + (2 + xcd) * 16, 1,
                                             __ATOMIC_RELAXED,
                                             __HIP_MEMORY_SCOPE_AGENT);
    __hip_atomic_fetch_add(elect, 1, __ATOMIC_ACQ_REL, __HIP_MEMORY_SCOPE_AGENT);
    while (__hip_atomic_load(elect, __ATOMIC_ACQUIRE,
                             __HIP_MEMORY_SCOPE_AGENT) < 256) {
    }
    int cnt[8];
    bool even = true;
    for (int j = 0; j < 8; ++j) {
      cnt[j] = __hip_atomic_load(elect + (2 + j) * 16, __ATOMIC_RELAXED,
                                 __HIP_MEMORY_SCOPE_AGENT);
      even = even && (cnt[j] == 32);
    }
    int bg, sl;
    if (local < 32) {
      bg = xcd;
      sl = local;
    } else {  // overflow: claim k-th deficit slot (deterministic enumeration)
      int k = __hip_atomic_fetch_add(elect + 16, 1, __ATOMIC_RELAXED,
                                     __HIP_MEMORY_SCOPE_AGENT);
      bg = 0;
      sl = 0;
      for (int j = 0; j < 8; ++j) {
        const int d = cnt[j] < 32 ? 32 - cnt[j] : 0;
        if (k < d) {
          bg = j;
          sl = cnt[j] + k;
          break;
        }
        k -= d;
      }
    }
    s_meta[0] = bg;
    s_meta[1] = sl;
    s_meta[2] = even ? 1 : 0;  // overflow implies !even -> GLOBAL for all
  }
  __syncthreads();
  const int bg = s_meta[0];
  const int sl = s_meta[1];
  const bool local_mode = s_meta[2] != 0;
  const int u0 = sl * USL;

  // ---- one-time: preformat Wr slice into LDS (split bf16, B-frag order) ----
  {
    const int cidx = tid & 63;        // gg*16+u within slice
    const int koff = tid >> 6;        // 0..3
    const int gg = cidx >> 4, u = cidx & 15;
    const int col = gg * UU + u0 + u;
    for (int k0 = 0; k0 < DD; k0 += 4) {
      const int k = k0 + koff;
      const float v = Wr[(size_t)k * NZ + col];
      const __hip_bfloat16 vh = __float2bfloat16(v);
      const float rem = v - __bfloat162float(vh);
      const __hip_bfloat16 vl = __float2bfloat16(rem);
      const int K = k >> 5, kg = (k >> 3) & 3, j = k & 7;
      const int off = ((K * 4 + gg) * 64 + (kg * 16 + u)) * 8 + j;
      wr_hi[off] = *(const unsigned short*)&vh;
      wr_lo[off] = *(const unsigned short*)&vl;
    }
  }
  __syncthreads();

  // MFMA A-fragment addressing: m-row am maps to local batch am&7 (rows 8-15
  // duplicate 0-7; C rows 8-15 ignored). Plane layout: [t][bg][8 b][512 u].
  const int am = lane & 15, akg = lane >> 4;
  const size_t arow = (size_t)(am & 7) * UU + akg * 8;  // ushort idx in plane

  // epilogue mapping (tid < 128): thread -> (local batch eb, unit eu)
  const int eb = tid >> 4;            // 0..7 for tid<128
  const int eu = tid & 15;
  const int b = bg * BG + eb;         // global batch
  const float bias_i = bias[0 * UU + u0 + eu];
  const float bias_f = bias[1 * UU + u0 + eu];
  const float bias_g = bias[2 * UU + u0 + eu];
  const float bias_o = bias[3 * UU + u0 + eu];
  float c_state = 0.f;
  const size_t plane_t = (size_t)NBG * BG * UU;  // 32768 ushorts per timestep
  // packed-pair 32-bit word index within a (t,bg) plane:
  const int wword_loc = (eb * UU + u0 + eu) >> 1;

  int* myflag = flags + (bg * NSL + sl) * 16;

  for (int t = 0; t < TT; ++t) {
    // ---- zx prefetch for this step (independent of h_t) ----
    float zi = 0.f, zf = 0.f, zg = 0.f, zo = 0.f;
    if (tid < 128) {
      const size_t zb = ((size_t)b * TT + t) * NZ + u0 + eu;
      if constexpr (ZXBF16) {
        const unsigned short* zx = (const unsigned short*)zx_;
        zi = __bfloat162float(*(const __hip_bfloat16*)&zx[zb + 0 * UU]);
        zf = __bfloat162float(*(const __hip_bfloat16*)&zx[zb + 1 * UU]);
        zg = __bfloat162float(*(const __hip_bfloat16*)&zx[zb + 2 * UU]);
        zo = __bfloat162float(*(const __hip_bfloat16*)&zx[zb + 3 * UU]);
      } else {
        const float* zx = (const float*)zx_;
        zi = zx[zb + 0 * UU];
        zf = zx[zb + 1 * UU];
        zg = zx[zb + 2 * UU];
        zo = zx[zb + 3 * UU];
      }
    }

    // ---- acquire h_t: relaxed poll of this bg's 32 flags, then wg fence ----
    if (tid < NSL) {
      const int* fp = flags + (bg * NSL + tid) * 16;
      while (__hip_atomic_load(fp, __ATOMIC_RELAXED, __HIP_MEMORY_SCOPE_AGENT) < t) {
      }
    }
    __syncthreads();
    __builtin_amdgcn_fence(__ATOMIC_ACQUIRE, "workgroup");

    // ---- z[8b dup x16][16u] for gate g via split-bf16 MFMA ----
    const unsigned short* Ahi =
        h_hi + ((size_t)t * NBG + bg) * (BG * UU) + arow;
    const unsigned short* Alo =
        h_lo + ((size_t)t * NBG + bg) * (BG * UU) + arow;
    floatx4 a0 = {0, 0, 0, 0}, a1 = {0, 0, 0, 0}, a2 = {0, 0, 0, 0};
#pragma unroll 4
    for (int K = 0; K < KSTEPS; ++K) {
      const short8 ahi = *(const short8*)(Ahi + K * 32);
      const short8 alo = *(const short8*)(Alo + K * 32);
      const short8 bhi = *(const short8*)(wr_hi + ((K * 4 + g) * 64 + lane) * 8);
      const short8 blo = *(const short8*)(wr_lo + ((K * 4 + g) * 64 + lane) * 8);
      a0 = mfma16(ahi, bhi, a0);
      a1 = mfma16(ahi, blo, a1);
      a2 = mfma16(alo, bhi, a2);
    }
    // C layout: u = lane&15, m-row = (lane>>4)*4 + r (rows 8-15 duplicates)
#pragma unroll
    for (int r = 0; r < 4; ++r) {
      const int rr = (lane >> 4) * 4 + r;
      z_ex[(g * 16 + rr) * 16 + (lane & 15)] = a0[r] + a1[r] + a2[r];
    }
    __syncthreads();

    if (tid < 128) {
      // ---- pointwise gates: thread = (eb, eu) ----
      zi += z_ex[(0 * 16 + eb) * 16 + eu] + bias_i;
      zf += z_ex[(1 * 16 + eb) * 16 + eu] + bias_f;
      zg += z_ex[(2 * 16 + eb) * 16 + eu] + bias_g;
      zo += z_ex[(3 * 16 + eb) * 16 + eu] + bias_o;

      const float ig = 1.f / (1.f + expf(-zi));
      const float fg = 1.f / (1.f + expf(-zf));
      const float gg = tanhf(zg);
      const float og = 1.f / (1.f + expf(-zo));
      c_state = fg * c_state + ig * gg;
      const float hn = og * tanhf(c_state);

      // split-bf16; pack pair-words via shfl; even-u threads store
      const __hip_bfloat16 hh = __float2bfloat16(hn);
      const float hrem = hn - __bfloat162float(hh);
      const __hip_bfloat16 hl = __float2bfloat16(hrem);
      const unsigned int vhi = (unsigned int)*(const unsigned short*)&hh;
      const unsigned int vlo = (unsigned int)*(const unsigned short*)&hl;
      const unsigned int nhi = (unsigned int)__shfl_xor((int)vhi, 1);
      const unsigned int nlo = (unsigned int)__shfl_xor((int)vlo, 1);
      if ((eu & 1) == 0) {
        const unsigned int whi = vhi | (nhi << 16);
        const unsigned int wlo = vlo | (nlo << 16);
        const size_t wbase = ((size_t)(t + 1) * NBG + bg) * (BG * UU / 2);
        unsigned int* phi = (unsigned int*)h_hi + wbase + wword_loc;
        unsigned int* plo = (unsigned int*)h_lo + wbase + wword_loc;
        if (local_mode) {
          *phi = whi;   // write-through to XCD-local L2
          *plo = wlo;
        } else {
          __hip_atomic_store(phi, whi, __ATOMIC_RELAXED, __HIP_MEMORY_SCOPE_AGENT);
          __hip_atomic_store(plo, wlo, __ATOMIC_RELAXED, __HIP_MEMORY_SCOPE_AGENT);
        }
      }
      if (t == TT - 1) out[(size_t)b * UU + u0 + eu] = hn;
    }

    // ---- release: barrier drains vmcnt (stores committed), then flag ----
    __syncthreads();
    if (tid == 0)
      __hip_atomic_store(myflag, t + 1, __ATOMIC_RELAXED,
                         __HIP_MEMORY_SCOPE_AGENT);
  }
}

// ---------------------------------------------------------------------------
extern "C" void kernel_launch(void* const* d_in, const int* in_sizes, int n_in,
                              void* d_out, int out_size, void* d_ws, size_t ws_size,
                              hipStream_t stream) {
  const float* x    = (const float*)d_in[0];
  const float* Wk   = (const float*)d_in[1];
  const float* Wr   = (const float*)d_in[2];
  const float* bias = (const float*)d_in[3];
  float* out = (float*)d_out;

  const size_t plane_t = (size_t)NBG * BG * UU;                 // 32768
  const size_t hplane_bytes = (size_t)(TT + 1) * plane_t * 2;   // 32.06 MiB
  const size_t flags_bytes = (size_t)NBG * NSL * 16 * 4;        // 16 KiB
  const size_t elect_bytes = (size_t)(2 + 8) * 16 * 4;          // 640 B
  const size_t zx_f32_bytes = (size_t)BSZ * TT * NZ * 4;        // 256 MiB

  const size_t need_f32 =
      zx_f32_bytes + 2 * hplane_bytes + flags_bytes + elect_bytes;
  const bool use_bf16_zx = (ws_size < need_f32);
  const size_t zx_bytes = use_bf16_zx ? zx_f32_bytes / 2 : zx_f32_bytes;

  char* ws = (char*)d_ws;
  void* zx = (void*)ws;
  unsigned short* h_hi = (unsigned short*)(ws + zx_bytes);
  unsigned short* h_lo = (unsigned short*)(ws + zx_bytes + hplane_bytes);
  int* flags = (int*)(ws + zx_bytes + 2 * hplane_bytes);
  int* elect = (int*)(ws + zx_bytes + 2 * hplane_bytes + flags_bytes);

  hipMemsetAsync(h_hi, 0, plane_t * 2, stream);  // h_0 slab (all bgs)
  hipMemsetAsync(h_lo, 0, plane_t * 2, stream);
  hipMemsetAsync(flags, 0, flags_bytes, stream);
  hipMemsetAsync(elect, 0, elect_bytes, stream);

  dim3 ggrid(NZ / 64, (BSZ * TT) / 64);
  if (use_bf16_zx)
    gemm_zx<true><<<ggrid, 256, 0, stream>>>(x, Wk, zx);
  else
    gemm_zx<false><<<ggrid, 256, 0, stream>>>(x, Wk, zx);

  // LDS: Wr hi/lo 128 KiB + z_ex 4 KiB + meta 64 B  (>80 KiB -> 1 block/CU)
  const int lds_bytes = KSTEPS * 4 * 64 * 8 * 2 * 2 + 4 * 16 * 16 * 4 + 64;
  if (use_bf16_zx) {
    hipFuncSetAttribute(reinterpret_cast<const void*>(lstm_persist<true>),
                        hipFuncAttributeMaxDynamicSharedMemorySize, lds_bytes);
    lstm_persist<true><<<256, 256, lds_bytes, stream>>>(zx, Wr, bias, h_hi, h_lo,
                                                        flags, elect, out);
  } else {
    hipFuncSetAttribute(reinterpret_cast<const void*>(lstm_persist<false>),
                        hipFuncAttributeMaxDynamicSharedMemorySize, lds_bytes);
    lstm_persist<false><<<256, 256, lds_bytes, stream>>>(zx, Wr, bias, h_hi, h_lo,
                                                         flags, elect, out);
  }
}